// Round 1
// baseline (523.555 us; speedup 1.0000x reference)
//
#include <hip/hip_runtime.h>

// B=128, K=1024 pairwise-distance adjacency + row softmax.
//
// v2 structure: chunked blocks. Each block owns 64 consecutive rows of one
// batch (16 tiles x 4 waves), stages the batch's 12 KB of coords ONCE, and
// each wave hoists its 16 j-points into 48 VGPRs -- the j-points are the
// same for every row, so the per-row LDS re-read (12x ds_read_b128) is
// eliminated. Output is write-once -> nontemporal dwordx4 stores.
//
// Softmax uses the constant shift: diagonal d_ii == 0 exactly (direct
// (xi-xj)^2 form), so row max of exp(-p*d) is exactly 1.0 -> no max pass.

#define K_PTS 1024
#define THREADS 256            // 4 waves, one row per wave per tile
#define TILES_PER_BLOCK 16     // 64 rows per block
#define BLOCKS_PER_BATCH 16    // 16 blocks * 64 rows = 1024 rows

typedef float vf4 __attribute__((ext_vector_type(4)));

__global__ __launch_bounds__(THREADS, 4) void adj_softmax_kernel(
    const float* __restrict__ coords,   // [B, K, 3]
    const float* __restrict__ prec,     // [1]
    float* __restrict__ out,            // [B, K, K]
    int B) {
  __shared__ float sx[K_PTS];
  __shared__ float sy[K_PTS];
  __shared__ float sz[K_PTS];

  const int tid   = threadIdx.x;
  const int lane  = tid & 63;
  const int wave  = tid >> 6;
  const int b     = blockIdx.x / BLOCKS_PER_BATCH;
  const int chunk = blockIdx.x % BLOCKS_PER_BATCH;

  const float p  = prec[0];
  const float np = -p;

  // ---- stage this batch's coords into LDS, deinterleaved (x|y|z) ----
  // 1024 points * 3 floats = 768 float4; 3 float4 per thread. Once per block.
  {
    const float* cb = coords + (size_t)b * (K_PTS * 3);
    const int p0 = tid * 4;                       // 4 points per thread
    const float4* src = (const float4*)(cb + (size_t)p0 * 3);
    float4 a0 = src[0];   // {x0,y0,z0,x1}
    float4 a1 = src[1];   // {y1,z1,x2,y2}
    float4 a2 = src[2];   // {z2,x3,y3,z3}
    sx[p0 + 0] = a0.x; sy[p0 + 0] = a0.y; sz[p0 + 0] = a0.z;
    sx[p0 + 1] = a0.w; sy[p0 + 1] = a1.x; sz[p0 + 1] = a1.y;
    sx[p0 + 2] = a1.z; sy[p0 + 2] = a1.w; sz[p0 + 2] = a2.x;
    sx[p0 + 3] = a2.y; sy[p0 + 3] = a2.z; sz[p0 + 3] = a2.w;
  }
  __syncthreads();

  // ---- hoist this lane's 16 j-points into registers (48 VGPRs) ----
  // A wave's 64 lanes collectively hold all 1024 points; every row this
  // wave computes reuses them. ds_read_b128, conflict-free (2-way = free).
  float4 vx[4], vy[4], vz[4];
#pragma unroll
  for (int t = 0; t < 4; ++t) {
    const int j0 = 4 * lane + 256 * t;
    vx[t] = *(const float4*)&sx[j0];
    vy[t] = *(const float4*)&sy[j0];
    vz[t] = *(const float4*)&sz[j0];
  }

  float* ob = out + (size_t)b * K_PTS * K_PTS;

  for (int it = 0; it < TILES_PER_BLOCK; ++it) {
    const int i = chunk * (TILES_PER_BLOCK * 4) + it * 4 + wave;  // wave's row
    // per-wave-uniform broadcast reads (same addr across lanes: free)
    const float xi = sx[i];
    const float yi = sy[i];
    const float zi = sz[i];

    vf4 e[4];
    float acc = 0.0f;

#pragma unroll
    for (int t = 0; t < 4; ++t) {
      float dx, dy, dz, d, xv;
      vf4 ev;

      dx = vx[t].x - xi; dy = vy[t].x - yi; dz = vz[t].x - zi;
      d  = fmaf(dx, dx, fmaf(dy, dy, dz * dz));
      xv = __expf(np * d);
      ev.x = __expf(xv - 1.0f);

      dx = vx[t].y - xi; dy = vy[t].y - yi; dz = vz[t].y - zi;
      d  = fmaf(dx, dx, fmaf(dy, dy, dz * dz));
      xv = __expf(np * d);
      ev.y = __expf(xv - 1.0f);

      dx = vx[t].z - xi; dy = vy[t].z - yi; dz = vz[t].z - zi;
      d  = fmaf(dx, dx, fmaf(dy, dy, dz * dz));
      xv = __expf(np * d);
      ev.z = __expf(xv - 1.0f);

      dx = vx[t].w - xi; dy = vy[t].w - yi; dz = vz[t].w - zi;
      d  = fmaf(dx, dx, fmaf(dy, dy, dz * dz));
      xv = __expf(np * d);
      ev.w = __expf(xv - 1.0f);

      e[t] = ev;
      acc += (ev.x + ev.y) + (ev.z + ev.w);
    }

    // ---- wave-level reduction (64 lanes) for the softmax denominator ----
#pragma unroll
    for (int off = 32; off > 0; off >>= 1) {
      acc += __shfl_xor(acc, off, 64);
    }
    const float inv = 1.0f / acc;

    // ---- normalized, coalesced nontemporal float4 stores ----
    float* orow = ob + (size_t)i * K_PTS;
#pragma unroll
    for (int t = 0; t < 4; ++t) {
      vf4 ev = e[t] * inv;
      __builtin_nontemporal_store(ev, (vf4*)&orow[4 * lane + 256 * t]);
    }
  }
}

extern "C" void kernel_launch(void* const* d_in, const int* in_sizes, int n_in,
                              void* d_out, int out_size, void* d_ws, size_t ws_size,
                              hipStream_t stream) {
  const float* coords = (const float*)d_in[0];   // [B, K, 3] fp32
  const float* prec   = (const float*)d_in[1];   // [1] fp32
  float* out = (float*)d_out;                    // [B, K, K] fp32

  const int B = in_sizes[0] / (K_PTS * 3);       // 128
  const int grid = B * BLOCKS_PER_BATCH;         // 128 * 16 = 2048 blocks

  adj_softmax_kernel<<<grid, THREADS, 0, stream>>>(coords, prec, out, B);
}